// Round 1
// baseline (5823.798 us; speedup 1.0000x reference)
//
#include <hip/hip_runtime.h>

#define E 16
#define HID 32
#define NSTEP 10
#define TAU 0.5f
#define SIGMA 0.5f
#define RES 0.5f

__device__ __forceinline__ float fast_tanh(float v) {
    float e = __expf(2.0f * v);
    return 1.0f - __fdividef(2.0f, e + 1.0f);
}
// scale = 1/max(sqrt(n2),1) == min(rsq(n2), 1)   (n2=0 -> rsq=inf -> min -> 1)
__device__ __forceinline__ float inv_norm_clamped(float n2) {
    return fminf(__builtin_amdgcn_rsqf(n2), 1.0f);
}

// waves_per_eu(4,4): 128-VGPR budget, predictable occupancy (R3 lesson: letting
// the scheduler chase 8 waves/EU caused spills). LDS 9.9KB/block -> 4 blocks/CU OK.
__global__ __attribute__((amdgpu_waves_per_eu(4, 4))) __launch_bounds__(256)
void pdhg_kernel(
    const float* __restrict__ xg,  const float* __restrict__ Gg,  const float* __restrict__ hg,
    const float* __restrict__ W1,  const float* __restrict__ b1,
    const float* __restrict__ W2,  const float* __restrict__ b2,
    const float* __restrict__ Wmu, const float* __restrict__ bmu,
    const float* __restrict__ Wy,  const float* __restrict__ by,
    const float* __restrict__ Wp1, const float* __restrict__ bp1,
    const float* __restrict__ Wp2, const float* __restrict__ bp2,
    float* __restrict__ out, int npts)
{
    // ---- LDS-staged constants: weight streaming off the SGPR path ----
    // (SGPR file was maxed at 112 -> v_writelane/readlane + v_mov bloat ate
    //  ~2/3 of VALU issue. ds_read_b128 w/ imm offsets costs zero VALU.)
    __shared__ __align__(16) float sL1[128];   // [32][4]: W1[j], W1[32+j], b1[j], pad
    __shared__ __align__(16) float sW2[1024];  // [32][32] row-major
    __shared__ __align__(16) float sB2[32];
    __shared__ __align__(16) float sWmu[512];  // [32][16] row-major
    __shared__ __align__(16) float sBmu[16];
    __shared__ __align__(16) float sWy[64];    // [32][2] interleaved
    __shared__ __align__(16) float sP1[128];   // [32][4]: Wp1[k], Wp1[32+k], bp1[k], pad
    __shared__ __align__(16) float sWp2[512];  // [32][16] row-major
    __shared__ __align__(16) float sBp2[16];
    __shared__ __align__(16) float sG[32];     // [16][2] interleaved (gx, gy)
    __shared__ float sBy[2];
    __shared__ float sH[16];

    const int tid = threadIdx.x;
    for (int i = tid; i < 1024; i += 256) sW2[i] = W2[i];
    for (int i = tid; i < 512;  i += 256) sWmu[i] = Wmu[i];
    for (int i = tid; i < 512;  i += 256) sWp2[i] = Wp2[i];
    if (tid < 32) {
        sL1[4 * tid + 0] = W1[tid];
        sL1[4 * tid + 1] = W1[HID + tid];
        sL1[4 * tid + 2] = b1[tid];
        sL1[4 * tid + 3] = 0.0f;
        sP1[4 * tid + 0] = Wp1[tid];
        sP1[4 * tid + 1] = Wp1[HID + tid];
        sP1[4 * tid + 2] = bp1[tid];
        sP1[4 * tid + 3] = 0.0f;
        sB2[tid] = b2[tid];
        sWy[2 * tid]     = Wy[2 * tid];
        sWy[2 * tid + 1] = Wy[2 * tid + 1];
        sG[tid] = Gg[tid];
    }
    if (tid < 16) { sBmu[tid] = bmu[tid]; sBp2[tid] = bp2[tid]; sH[tid] = hg[tid]; }
    if (tid < 2)  sBy[tid] = by[tid];
    __syncthreads();

    const int t = blockIdx.x * blockDim.x + tid;
    if (t >= npts) return;

    const float2 xv = reinterpret_cast<const float2*>(xg)[t];
    const float x0 = xv.x, x1 = xv.y;

    const float4* sL1v  = reinterpret_cast<const float4*>(sL1);
    const float4* sB2v  = reinterpret_cast<const float4*>(sB2);
    const float4* sBmuv = reinterpret_cast<const float4*>(sBmu);
    const float4* sP1v  = reinterpret_cast<const float4*>(sP1);
    const float4* sBp2v = reinterpret_cast<const float4*>(sBp2);
    const float2* sG2   = reinterpret_cast<const float2*>(sG);
    const float2* sWy2  = reinterpret_cast<const float2*>(sWy);

    // ---------------- encoder layer 1: relu(x @ W1 + b1) ----------------
    float f[HID];
    #pragma unroll
    for (int j = 0; j < HID; ++j) {
        const float4 w = sL1v[j];                     // one ds_read_b128: w0,w1,b
        f[j] = fmaxf(fmaf(x0, w.x, fmaf(x1, w.y, w.z)), 0.0f);
    }

    // ---------------- encoder layer 2 (row-major i-outer, b128 row reads) ----
    float g[HID];
    #pragma unroll
    for (int q = 0; q < 8; ++q) {
        const float4 b = sB2v[q];
        g[4 * q + 0] = b.x; g[4 * q + 1] = b.y; g[4 * q + 2] = b.z; g[4 * q + 3] = b.w;
    }
    #pragma unroll
    for (int i = 0; i < HID; ++i) {
        const float fi = f[i];
        const float4* wrow = reinterpret_cast<const float4*>(sW2 + i * HID);
        #pragma unroll
        for (int q = 0; q < 8; ++q) {
            const float4 w = wrow[q];
            g[4 * q + 0] = fmaf(fi, w.x, g[4 * q + 0]);
            g[4 * q + 1] = fmaf(fi, w.y, g[4 * q + 1]);
            g[4 * q + 2] = fmaf(fi, w.z, g[4 * q + 2]);
            g[4 * q + 3] = fmaf(fi, w.w, g[4 * q + 3]);
        }
    }
    #pragma unroll
    for (int j = 0; j < HID; ++j) g[j] = fmaxf(g[j], 0.0f);
    // f dead from here

    // ---------------- heads: mu = relu(g@Wmu+bmu), y = tanh(g@Wy+by) ----------
    float mu[E];
    #pragma unroll
    for (int q = 0; q < 4; ++q) {
        const float4 b = sBmuv[q];
        mu[4 * q + 0] = b.x; mu[4 * q + 1] = b.y; mu[4 * q + 2] = b.z; mu[4 * q + 3] = b.w;
    }
    float y0 = sBy[0], y1 = sBy[1];
    #pragma unroll
    for (int j = 0; j < HID; ++j) {
        const float gj = g[j];
        const float4* wrow = reinterpret_cast<const float4*>(sWmu + j * E);
        #pragma unroll
        for (int q = 0; q < 4; ++q) {
            const float4 w = wrow[q];
            mu[4 * q + 0] = fmaf(gj, w.x, mu[4 * q + 0]);
            mu[4 * q + 1] = fmaf(gj, w.y, mu[4 * q + 1]);
            mu[4 * q + 2] = fmaf(gj, w.z, mu[4 * q + 2]);
            mu[4 * q + 3] = fmaf(gj, w.w, mu[4 * q + 3]);
        }
        const float2 wy = sWy2[j];
        y0 = fmaf(gj, wy.x, y0);
        y1 = fmaf(gj, wy.y, y1);
    }
    #pragma unroll
    for (int e = 0; e < E; ++e) mu[e] = fmaxf(mu[e], 0.0f);
    y0 = fast_tanh(y0);
    y1 = fast_tanh(y1);
    // g dead from here

    // ------- ta = TAU*(x@G^T - h) ; tc = TAU*(a@G) ; tg = TAU*GtG ; v = mu@G -------
    float ta[E];
    float tc0 = 0.f, tc1 = 0.f, g00 = 0.f, g01 = 0.f, g11 = 0.f;
    float v0 = 0.f, v1 = 0.f;
    #pragma unroll
    for (int e = 0; e < E; ++e) {
        const float2 ge = sG2[e];
        g00 = fmaf(ge.x, ge.x, g00);
        g01 = fmaf(ge.x, ge.y, g01);
        g11 = fmaf(ge.y, ge.y, g11);
        const float ae = fmaf(x0, ge.x, fmaf(x1, ge.y, -sH[e]));
        const float tae = TAU * ae;
        ta[e] = tae;
        tc0 = fmaf(tae, ge.x, tc0);   // accumulates TAU*c directly
        tc1 = fmaf(tae, ge.y, tc1);
        v0 = fmaf(mu[e], ge.x, v0);
        v1 = fmaf(mu[e], ge.y, v1);
    }
    const float tg00 = TAU * g00, tg01 = TAU * g01, tg11 = TAU * g11;

    // ---------------- PDHG steps ----------------
    #pragma unroll 1
    for (int s = 0; s < NSTEP; ++s) {
        // y += SIGMA*v (v == mu@G maintained incrementally); unit-ball project
        y0 = fmaf(SIGMA, v0, y0);
        y1 = fmaf(SIGMA, v1, y1);
        {
            const float sc = inv_norm_clamped(fmaf(y0, y0, y1 * y1));
            y0 *= sc; y1 *= sc;
        }

        // z = mu'@G without the dot: z = v + TAU*c - TAU*GtG@y  (tg,tc prefolded)
        const float z0 = fmaf(-tg00, y0, fmaf(-tg01, y1, v0 + tc0));
        const float z1 = fmaf(-tg01, y0, fmaf(-tg11, y1, v1 + tc1));

        // mu += TAU*(a - y@G^T) == mu + ta - yt0*gx - yt1*gy   (3 VALU/e, neg mods free)
        const float yt0 = TAU * y0, yt1 = TAU * y1;
        #pragma unroll
        for (int e = 0; e < E; ++e) {
            const float2 ge = sG2[e];
            mu[e] = fmaf(-yt1, ge.y, fmaf(-yt0, ge.x, mu[e] + ta[e]));
        }

        // fused prox head: hidden value produced & immediately consumed
        float dl[E];
        #pragma unroll
        for (int q = 0; q < 4; ++q) {
            const float4 b = sBp2v[q];
            dl[4 * q + 0] = b.x; dl[4 * q + 1] = b.y; dl[4 * q + 2] = b.z; dl[4 * q + 3] = b.w;
        }
        #pragma unroll
        for (int k = 0; k < HID; ++k) {
            const float4 wp = sP1v[k];                 // one b128: wa, wb, bias
            const float hk = fmaxf(fmaf(z0, wp.x, fmaf(z1, wp.y, wp.z)), 0.0f);
            const float4* w2r = reinterpret_cast<const float4*>(sWp2 + k * E);
            #pragma unroll
            for (int q = 0; q < 4; ++q) {
                const float4 w = w2r[q];
                dl[4 * q + 0] = fmaf(hk, w.x, dl[4 * q + 0]);
                dl[4 * q + 1] = fmaf(hk, w.y, dl[4 * q + 1]);
                dl[4 * q + 2] = fmaf(hk, w.z, dl[4 * q + 2]);
                dl[4 * q + 3] = fmaf(hk, w.w, dl[4 * q + 3]);
            }
        }

        // mu = project_mu(mu + RES*dl); maintain v = sc * (pre-scale mu@G)
        float p0 = 0.f, p1 = 0.f;
        #pragma unroll
        for (int e = 0; e < E; ++e) {
            const float m = fmaxf(fmaf(RES, dl[e], mu[e]), 0.0f);
            mu[e] = m;
            const float2 ge = sG2[e];
            p0 = fmaf(m, ge.x, p0);
            p1 = fmaf(m, ge.y, p1);
        }
        const float sc = inv_norm_clamped(fmaf(p0, p0, p1 * p1));
        #pragma unroll
        for (int e = 0; e < E; ++e) mu[e] *= sc;
        v0 = sc * p0;
        v1 = sc * p1;
    }

    // final project_mu is the identity here: mu >= 0 and ||mu@G|| <= 1 already.

    // ---------------- store 16 contiguous floats ----------------
    float4* outv = reinterpret_cast<float4*>(out + (size_t)t * E);
    outv[0] = make_float4(mu[0],  mu[1],  mu[2],  mu[3]);
    outv[1] = make_float4(mu[4],  mu[5],  mu[6],  mu[7]);
    outv[2] = make_float4(mu[8],  mu[9],  mu[10], mu[11]);
    outv[3] = make_float4(mu[12], mu[13], mu[14], mu[15]);
}

extern "C" void kernel_launch(void* const* d_in, const int* in_sizes, int n_in,
                              void* d_out, int out_size, void* d_ws, size_t ws_size,
                              hipStream_t stream) {
    const float* x   = (const float*)d_in[0];
    const float* G   = (const float*)d_in[1];
    const float* h   = (const float*)d_in[2];
    const float* W1  = (const float*)d_in[3];
    const float* b1  = (const float*)d_in[4];
    const float* W2  = (const float*)d_in[5];
    const float* b2  = (const float*)d_in[6];
    const float* Wmu = (const float*)d_in[7];
    const float* bmu = (const float*)d_in[8];
    const float* Wy  = (const float*)d_in[9];
    const float* by  = (const float*)d_in[10];
    const float* Wp1 = (const float*)d_in[11];
    const float* bp1 = (const float*)d_in[12];
    const float* Wp2 = (const float*)d_in[13];
    const float* bp2 = (const float*)d_in[14];

    const int npts = in_sizes[0] / 2;   // x is [N,2]
    const int block = 256;
    const int grid = (npts + block - 1) / block;

    pdhg_kernel<<<grid, block, 0, stream>>>(x, G, h, W1, b1, W2, b2, Wmu, bmu,
                                            Wy, by, Wp1, bp1, Wp2, bp2,
                                            (float*)d_out, npts);
}

// Round 2
// 475.383 us; speedup vs baseline: 12.2508x; 12.2508x over previous
//
#include <hip/hip_runtime.h>

#define E 16
#define HID 32
#define NSTEP 10
#define TAU 0.5f
#define SIGMA 0.5f
#define RES 0.5f
#define P 2   // points per thread: weight scalars fetched once, used P times

__device__ __forceinline__ float fast_tanh(float v) {
    float e = __expf(2.0f * v);
    return 1.0f - __fdividef(2.0f, e + 1.0f);
}
// scale = 1/max(sqrt(n2),1) == min(rsq(n2), 1)   (n2=0 -> rsq=inf -> min -> 1)
__device__ __forceinline__ float inv_norm_clamped(float n2) {
    return fminf(__builtin_amdgcn_rsqf(n2), 1.0f);
}

// waves_per_eu(3,3): pin VGPR budget at ~170 (3 waves/EU). R1 lesson: LDS-staged
// weights -> VGPR pressure -> 15GB scratch spill. Weights stay on the SGPR/s_load
// path; P=2 halves per-point scalar-delivery cost. Estimated peak pressure ~125.
__global__ __attribute__((amdgpu_waves_per_eu(3, 3))) __launch_bounds__(256)
void pdhg_kernel(
    const float* __restrict__ xg,  const float* __restrict__ Gg,  const float* __restrict__ hg,
    const float* __restrict__ W1,  const float* __restrict__ b1,
    const float* __restrict__ W2,  const float* __restrict__ b2,
    const float* __restrict__ Wmu, const float* __restrict__ bmu,
    const float* __restrict__ Wy,  const float* __restrict__ by,
    const float* __restrict__ Wp1, const float* __restrict__ bp1,
    const float* __restrict__ Wp2, const float* __restrict__ bp2,
    float* __restrict__ out, int npts)
{
    const int half = (npts + 1) >> 1;
    const int t = blockIdx.x * blockDim.x + threadIdx.x;
    if (t >= half) return;

    const int i1 = t + half;
    const bool live1 = (i1 < npts);
    const int i1c = live1 ? i1 : t;   // clamped: harmless duplicate compute on odd tails

    float x0[P], x1[P];
    {
        const float2 a0 = reinterpret_cast<const float2*>(xg)[t];
        const float2 a1 = reinterpret_cast<const float2*>(xg)[i1c];
        x0[0] = a0.x; x1[0] = a0.y;
        x0[1] = a1.x; x1[1] = a1.y;
    }

    // ---------------- encoder: fused L1+L2, f in chunks of 8 (pressure cap) ----
    // g = relu( relu(x@W1+b1) @ W2 + b2 ); i-ascending accumulation == R0 rounding
    float g[P][HID];
    #pragma unroll
    for (int j = 0; j < HID; ++j) {
        const float bb = b2[j];
        #pragma unroll
        for (int p = 0; p < P; ++p) g[p][j] = bb;
    }
    #pragma unroll
    for (int ci = 0; ci < 4; ++ci) {
        float fc[P][8];
        #pragma unroll
        for (int jj = 0; jj < 8; ++jj) {
            const int j = ci * 8 + jj;
            const float w0 = W1[j], w1 = W1[HID + j], bb = b1[j];
            #pragma unroll
            for (int p = 0; p < P; ++p)
                fc[p][jj] = fmaxf(fmaf(x0[p], w0, fmaf(x1[p], w1, bb)), 0.0f);
        }
        #pragma unroll
        for (int ii = 0; ii < 8; ++ii) {
            const int i = ci * 8 + ii;
            #pragma unroll
            for (int j = 0; j < HID; ++j) {
                const float w = W2[i * HID + j];
                #pragma unroll
                for (int p = 0; p < P; ++p) g[p][j] = fmaf(fc[p][ii], w, g[p][j]);
            }
        }
    }
    #pragma unroll
    for (int j = 0; j < HID; ++j)
        #pragma unroll
        for (int p = 0; p < P; ++p) g[p][j] = fmaxf(g[p][j], 0.0f);

    // ---------------- heads: mu = relu(g@Wmu+bmu), y = tanh(g@Wy+by) ----------
    float mu[P][E];
    #pragma unroll
    for (int e = 0; e < E; ++e) {
        const float bb = bmu[e];
        #pragma unroll
        for (int p = 0; p < P; ++p) mu[p][e] = bb;
    }
    float y0[P], y1[P];
    {
        const float b0 = by[0], b1v = by[1];
        #pragma unroll
        for (int p = 0; p < P; ++p) { y0[p] = b0; y1[p] = b1v; }
    }
    #pragma unroll
    for (int j = 0; j < HID; ++j) {
        #pragma unroll
        for (int e = 0; e < E; ++e) {
            const float w = Wmu[j * E + e];
            #pragma unroll
            for (int p = 0; p < P; ++p) mu[p][e] = fmaf(g[p][j], w, mu[p][e]);
        }
        const float wy0 = Wy[j * 2], wy1 = Wy[j * 2 + 1];
        #pragma unroll
        for (int p = 0; p < P; ++p) {
            y0[p] = fmaf(g[p][j], wy0, y0[p]);
            y1[p] = fmaf(g[p][j], wy1, y1[p]);
        }
    }
    #pragma unroll
    for (int e = 0; e < E; ++e)
        #pragma unroll
        for (int p = 0; p < P; ++p) mu[p][e] = fmaxf(mu[p][e], 0.0f);
    #pragma unroll
    for (int p = 0; p < P; ++p) { y0[p] = fast_tanh(y0[p]); y1[p] = fast_tanh(y1[p]); }
    // g dead from here

    // ------- ta = TAU*(x@G^T - h) ; tc = TAU*(a@G) ; tg = TAU*GtG ; v = mu@G -------
    float ta[P][E];
    float tc0[P], tc1[P], v0[P], v1[P];
    float g00 = 0.f, g01 = 0.f, g11 = 0.f;
    #pragma unroll
    for (int p = 0; p < P; ++p) { tc0[p] = 0.f; tc1[p] = 0.f; v0[p] = 0.f; v1[p] = 0.f; }
    #pragma unroll
    for (int e = 0; e < E; ++e) {
        const float gx = Gg[2 * e], gy = Gg[2 * e + 1], he = hg[e];
        g00 = fmaf(gx, gx, g00);
        g01 = fmaf(gx, gy, g01);
        g11 = fmaf(gy, gy, g11);
        #pragma unroll
        for (int p = 0; p < P; ++p) {
            const float ae = fmaf(x0[p], gx, fmaf(x1[p], gy, -he));
            const float tae = TAU * ae;
            ta[p][e] = tae;
            tc0[p] = fmaf(tae, gx, tc0[p]);
            tc1[p] = fmaf(tae, gy, tc1[p]);
            v0[p] = fmaf(mu[p][e], gx, v0[p]);
            v1[p] = fmaf(mu[p][e], gy, v1[p]);
        }
    }
    const float tg00 = TAU * g00, tg01 = TAU * g01, tg11 = TAU * g11;
    // x dead from here

    // ---------------- PDHG steps ----------------
    #pragma unroll 1
    for (int s = 0; s < NSTEP; ++s) {
        float z0[P], z1[P], yt0[P], yt1[P];
        #pragma unroll
        for (int p = 0; p < P; ++p) {
            // y += SIGMA*v; unit-ball project
            y0[p] = fmaf(SIGMA, v0[p], y0[p]);
            y1[p] = fmaf(SIGMA, v1[p], y1[p]);
            const float sc = inv_norm_clamped(fmaf(y0[p], y0[p], y1[p] * y1[p]));
            y0[p] *= sc; y1[p] *= sc;
            // z = mu'@G without the dot: z = v + TAU*c - TAU*GtG@y
            z0[p] = fmaf(-tg00, y0[p], fmaf(-tg01, y1[p], v0[p] + tc0[p]));
            z1[p] = fmaf(-tg01, y0[p], fmaf(-tg11, y1[p], v1[p] + tc1[p]));
            yt0[p] = TAU * y0[p]; yt1[p] = TAU * y1[p];
        }

        // mu += TAU*(a - y@G^T) == mu + ta - yt0*gx - yt1*gy
        #pragma unroll
        for (int e = 0; e < E; ++e) {
            const float gx = Gg[2 * e], gy = Gg[2 * e + 1];
            #pragma unroll
            for (int p = 0; p < P; ++p)
                mu[p][e] = fmaf(-yt1[p], gy, fmaf(-yt0[p], gx, mu[p][e] + ta[p][e]));
        }

        // fused prox head: hidden value produced & immediately consumed
        float dl[P][E];
        #pragma unroll
        for (int e = 0; e < E; ++e) {
            const float bb = bp2[e];
            #pragma unroll
            for (int p = 0; p < P; ++p) dl[p][e] = bb;
        }
        #pragma unroll
        for (int k = 0; k < HID; ++k) {
            const float wa = Wp1[k], wb = Wp1[HID + k], bb = bp1[k];
            float hk[P];
            #pragma unroll
            for (int p = 0; p < P; ++p)
                hk[p] = fmaxf(fmaf(z0[p], wa, fmaf(z1[p], wb, bb)), 0.0f);
            #pragma unroll
            for (int e = 0; e < E; ++e) {
                const float w = Wp2[k * E + e];
                #pragma unroll
                for (int p = 0; p < P; ++p) dl[p][e] = fmaf(hk[p], w, dl[p][e]);
            }
        }

        // mu = project_mu(mu + RES*dl); maintain v = sc * (pre-scale mu@G)
        float p0a[P], p1a[P];
        #pragma unroll
        for (int p = 0; p < P; ++p) { p0a[p] = 0.f; p1a[p] = 0.f; }
        #pragma unroll
        for (int e = 0; e < E; ++e) {
            const float gx = Gg[2 * e], gy = Gg[2 * e + 1];
            #pragma unroll
            for (int p = 0; p < P; ++p) {
                const float m = fmaxf(fmaf(RES, dl[p][e], mu[p][e]), 0.0f);
                mu[p][e] = m;
                p0a[p] = fmaf(m, gx, p0a[p]);
                p1a[p] = fmaf(m, gy, p1a[p]);
            }
        }
        #pragma unroll
        for (int p = 0; p < P; ++p) {
            const float sc = inv_norm_clamped(fmaf(p0a[p], p0a[p], p1a[p] * p1a[p]));
            #pragma unroll
            for (int e = 0; e < E; ++e) mu[p][e] *= sc;
            v0[p] = sc * p0a[p];
            v1[p] = sc * p1a[p];
        }
    }

    // final project_mu is the identity here: mu >= 0 and ||mu@G|| <= 1 already.

    // ---------------- store 16 contiguous floats per point ----------------
    {
        float4* o = reinterpret_cast<float4*>(out + (size_t)t * E);
        o[0] = make_float4(mu[0][0],  mu[0][1],  mu[0][2],  mu[0][3]);
        o[1] = make_float4(mu[0][4],  mu[0][5],  mu[0][6],  mu[0][7]);
        o[2] = make_float4(mu[0][8],  mu[0][9],  mu[0][10], mu[0][11]);
        o[3] = make_float4(mu[0][12], mu[0][13], mu[0][14], mu[0][15]);
    }
    if (live1) {
        float4* o = reinterpret_cast<float4*>(out + (size_t)i1 * E);
        o[0] = make_float4(mu[1][0],  mu[1][1],  mu[1][2],  mu[1][3]);
        o[1] = make_float4(mu[1][4],  mu[1][5],  mu[1][6],  mu[1][7]);
        o[2] = make_float4(mu[1][8],  mu[1][9],  mu[1][10], mu[1][11]);
        o[3] = make_float4(mu[1][12], mu[1][13], mu[1][14], mu[1][15]);
    }
}

extern "C" void kernel_launch(void* const* d_in, const int* in_sizes, int n_in,
                              void* d_out, int out_size, void* d_ws, size_t ws_size,
                              hipStream_t stream) {
    const float* x   = (const float*)d_in[0];
    const float* G   = (const float*)d_in[1];
    const float* h   = (const float*)d_in[2];
    const float* W1  = (const float*)d_in[3];
    const float* b1  = (const float*)d_in[4];
    const float* W2  = (const float*)d_in[5];
    const float* b2  = (const float*)d_in[6];
    const float* Wmu = (const float*)d_in[7];
    const float* bmu = (const float*)d_in[8];
    const float* Wy  = (const float*)d_in[9];
    const float* by  = (const float*)d_in[10];
    const float* Wp1 = (const float*)d_in[11];
    const float* bp1 = (const float*)d_in[12];
    const float* Wp2 = (const float*)d_in[13];
    const float* bp2 = (const float*)d_in[14];

    const int npts = in_sizes[0] / 2;   // x is [N,2]
    const int half = (npts + 1) >> 1;   // P=2 points per thread
    const int block = 256;
    const int grid = (half + block - 1) / block;

    pdhg_kernel<<<grid, block, 0, stream>>>(x, G, h, W1, b1, W2, b2, Wmu, bmu,
                                            Wy, by, Wp1, bp1, Wp2, bp2,
                                            (float*)d_out, npts);
}

// Round 3
// 465.642 us; speedup vs baseline: 12.5070x; 1.0209x over previous
//
#include <hip/hip_runtime.h>

#define E 16
#define HID 32
#define NSTEP 10
#define TAU 0.5f
#define SIGMA 0.5f
#define RES 0.5f
#define P 2   // points per thread: weight scalars fetched once, used P times

__device__ __forceinline__ float fast_tanh(float v) {
    float e = __expf(2.0f * v);
    return 1.0f - __fdividef(2.0f, e + 1.0f);
}
// scale = 1/max(sqrt(n2),1) == min(rsq(n2), 1)   (n2=0 -> rsq=inf -> min -> 1)
__device__ __forceinline__ float inv_norm_clamped(float n2) {
    return fminf(__builtin_amdgcn_rsqf(n2), 1.0f);
}

// waves_per_eu(4,6): R2 ran VGPR=68 but (3,3) self-capped occupancy at 31%
// (2.5 waves/SIMD) -> s_load latency exposed. min=4 keeps a 128-VGPR hard
// budget (no spill pressure at 68 in use); max=6 bounds the allocator's
// chase-the-max behavior at ~85 VGPR (R3 lesson: chasing 8 -> 64 VGPR -> spill).
__global__ __attribute__((amdgpu_waves_per_eu(4, 6))) __launch_bounds__(256)
void pdhg_kernel(
    const float* __restrict__ xg,  const float* __restrict__ Gg,  const float* __restrict__ hg,
    const float* __restrict__ W1,  const float* __restrict__ b1,
    const float* __restrict__ W2,  const float* __restrict__ b2,
    const float* __restrict__ Wmu, const float* __restrict__ bmu,
    const float* __restrict__ Wy,  const float* __restrict__ by,
    const float* __restrict__ Wp1, const float* __restrict__ bp1,
    const float* __restrict__ Wp2, const float* __restrict__ bp2,
    float* __restrict__ out, int npts)
{
    const int half = (npts + 1) >> 1;
    const int t = blockIdx.x * blockDim.x + threadIdx.x;
    if (t >= half) return;

    const int i1 = t + half;
    const bool live1 = (i1 < npts);
    const int i1c = live1 ? i1 : t;   // clamped: harmless duplicate compute on odd tails

    float x0[P], x1[P];
    {
        const float2 a0 = reinterpret_cast<const float2*>(xg)[t];
        const float2 a1 = reinterpret_cast<const float2*>(xg)[i1c];
        x0[0] = a0.x; x1[0] = a0.y;
        x0[1] = a1.x; x1[1] = a1.y;
    }

    // ---------------- encoder: fused L1+L2, f in chunks of 8 (pressure cap) ----
    // g = relu( relu(x@W1+b1) @ W2 + b2 ); i-ascending accumulation == R0 rounding
    float g[P][HID];
    #pragma unroll
    for (int j = 0; j < HID; ++j) {
        const float bb = b2[j];
        #pragma unroll
        for (int p = 0; p < P; ++p) g[p][j] = bb;
    }
    #pragma unroll
    for (int ci = 0; ci < 4; ++ci) {
        float fc[P][8];
        #pragma unroll
        for (int jj = 0; jj < 8; ++jj) {
            const int j = ci * 8 + jj;
            const float w0 = W1[j], w1 = W1[HID + j], bb = b1[j];
            #pragma unroll
            for (int p = 0; p < P; ++p)
                fc[p][jj] = fmaxf(fmaf(x0[p], w0, fmaf(x1[p], w1, bb)), 0.0f);
        }
        #pragma unroll
        for (int ii = 0; ii < 8; ++ii) {
            const int i = ci * 8 + ii;
            #pragma unroll
            for (int j = 0; j < HID; ++j) {
                const float w = W2[i * HID + j];
                #pragma unroll
                for (int p = 0; p < P; ++p) g[p][j] = fmaf(fc[p][ii], w, g[p][j]);
            }
        }
    }
    #pragma unroll
    for (int j = 0; j < HID; ++j)
        #pragma unroll
        for (int p = 0; p < P; ++p) g[p][j] = fmaxf(g[p][j], 0.0f);

    // ---------------- heads: mu = relu(g@Wmu+bmu), y = tanh(g@Wy+by) ----------
    float mu[P][E];
    #pragma unroll
    for (int e = 0; e < E; ++e) {
        const float bb = bmu[e];
        #pragma unroll
        for (int p = 0; p < P; ++p) mu[p][e] = bb;
    }
    float y0[P], y1[P];
    {
        const float b0 = by[0], b1v = by[1];
        #pragma unroll
        for (int p = 0; p < P; ++p) { y0[p] = b0; y1[p] = b1v; }
    }
    #pragma unroll
    for (int j = 0; j < HID; ++j) {
        #pragma unroll
        for (int e = 0; e < E; ++e) {
            const float w = Wmu[j * E + e];
            #pragma unroll
            for (int p = 0; p < P; ++p) mu[p][e] = fmaf(g[p][j], w, mu[p][e]);
        }
        const float wy0 = Wy[j * 2], wy1 = Wy[j * 2 + 1];
        #pragma unroll
        for (int p = 0; p < P; ++p) {
            y0[p] = fmaf(g[p][j], wy0, y0[p]);
            y1[p] = fmaf(g[p][j], wy1, y1[p]);
        }
    }
    #pragma unroll
    for (int e = 0; e < E; ++e)
        #pragma unroll
        for (int p = 0; p < P; ++p) mu[p][e] = fmaxf(mu[p][e], 0.0f);
    #pragma unroll
    for (int p = 0; p < P; ++p) { y0[p] = fast_tanh(y0[p]); y1[p] = fast_tanh(y1[p]); }
    // g dead from here

    // ------- ta = TAU*(x@G^T - h) ; tc = TAU*(a@G) ; tg = TAU*GtG ; v = mu@G -------
    float ta[P][E];
    float tc0[P], tc1[P], v0[P], v1[P];
    float g00 = 0.f, g01 = 0.f, g11 = 0.f;
    #pragma unroll
    for (int p = 0; p < P; ++p) { tc0[p] = 0.f; tc1[p] = 0.f; v0[p] = 0.f; v1[p] = 0.f; }
    #pragma unroll
    for (int e = 0; e < E; ++e) {
        const float gx = Gg[2 * e], gy = Gg[2 * e + 1], he = hg[e];
        g00 = fmaf(gx, gx, g00);
        g01 = fmaf(gx, gy, g01);
        g11 = fmaf(gy, gy, g11);
        #pragma unroll
        for (int p = 0; p < P; ++p) {
            const float ae = fmaf(x0[p], gx, fmaf(x1[p], gy, -he));
            const float tae = TAU * ae;
            ta[p][e] = tae;
            tc0[p] = fmaf(tae, gx, tc0[p]);
            tc1[p] = fmaf(tae, gy, tc1[p]);
            v0[p] = fmaf(mu[p][e], gx, v0[p]);
            v1[p] = fmaf(mu[p][e], gy, v1[p]);
        }
    }
    const float tg00 = TAU * g00, tg01 = TAU * g01, tg11 = TAU * g11;
    // x dead from here

    // ---------------- PDHG steps ----------------
    #pragma unroll 1
    for (int s = 0; s < NSTEP; ++s) {
        float z0[P], z1[P], yt0[P], yt1[P];
        #pragma unroll
        for (int p = 0; p < P; ++p) {
            // y += SIGMA*v; unit-ball project
            y0[p] = fmaf(SIGMA, v0[p], y0[p]);
            y1[p] = fmaf(SIGMA, v1[p], y1[p]);
            const float sc = inv_norm_clamped(fmaf(y0[p], y0[p], y1[p] * y1[p]));
            y0[p] *= sc; y1[p] *= sc;
            // z = mu'@G without the dot: z = v + TAU*c - TAU*GtG@y
            z0[p] = fmaf(-tg00, y0[p], fmaf(-tg01, y1[p], v0[p] + tc0[p]));
            z1[p] = fmaf(-tg01, y0[p], fmaf(-tg11, y1[p], v1[p] + tc1[p]));
            yt0[p] = TAU * y0[p]; yt1[p] = TAU * y1[p];
        }

        // mu += TAU*(a - y@G^T) == mu + ta - yt0*gx - yt1*gy
        #pragma unroll
        for (int e = 0; e < E; ++e) {
            const float gx = Gg[2 * e], gy = Gg[2 * e + 1];
            #pragma unroll
            for (int p = 0; p < P; ++p)
                mu[p][e] = fmaf(-yt1[p], gy, fmaf(-yt0[p], gx, mu[p][e] + ta[p][e]));
        }

        // fused prox head: hidden value produced & immediately consumed
        float dl[P][E];
        #pragma unroll
        for (int e = 0; e < E; ++e) {
            const float bb = bp2[e];
            #pragma unroll
            for (int p = 0; p < P; ++p) dl[p][e] = bb;
        }
        #pragma unroll
        for (int k = 0; k < HID; ++k) {
            const float wa = Wp1[k], wb = Wp1[HID + k], bb = bp1[k];
            float hk[P];
            #pragma unroll
            for (int p = 0; p < P; ++p)
                hk[p] = fmaxf(fmaf(z0[p], wa, fmaf(z1[p], wb, bb)), 0.0f);
            #pragma unroll
            for (int e = 0; e < E; ++e) {
                const float w = Wp2[k * E + e];
                #pragma unroll
                for (int p = 0; p < P; ++p) dl[p][e] = fmaf(hk[p], w, dl[p][e]);
            }
        }

        // mu = project_mu(mu + RES*dl); maintain v = sc * (pre-scale mu@G)
        float p0a[P], p1a[P];
        #pragma unroll
        for (int p = 0; p < P; ++p) { p0a[p] = 0.f; p1a[p] = 0.f; }
        #pragma unroll
        for (int e = 0; e < E; ++e) {
            const float gx = Gg[2 * e], gy = Gg[2 * e + 1];
            #pragma unroll
            for (int p = 0; p < P; ++p) {
                const float m = fmaxf(fmaf(RES, dl[p][e], mu[p][e]), 0.0f);
                mu[p][e] = m;
                p0a[p] = fmaf(m, gx, p0a[p]);
                p1a[p] = fmaf(m, gy, p1a[p]);
            }
        }
        #pragma unroll
        for (int p = 0; p < P; ++p) {
            const float sc = inv_norm_clamped(fmaf(p0a[p], p0a[p], p1a[p] * p1a[p]));
            #pragma unroll
            for (int e = 0; e < E; ++e) mu[p][e] *= sc;
            v0[p] = sc * p0a[p];
            v1[p] = sc * p1a[p];
        }
    }

    // final project_mu is the identity here: mu >= 0 and ||mu@G|| <= 1 already.

    // ---------------- store 16 contiguous floats per point ----------------
    {
        float4* o = reinterpret_cast<float4*>(out + (size_t)t * E);
        o[0] = make_float4(mu[0][0],  mu[0][1],  mu[0][2],  mu[0][3]);
        o[1] = make_float4(mu[0][4],  mu[0][5],  mu[0][6],  mu[0][7]);
        o[2] = make_float4(mu[0][8],  mu[0][9],  mu[0][10], mu[0][11]);
        o[3] = make_float4(mu[0][12], mu[0][13], mu[0][14], mu[0][15]);
    }
    if (live1) {
        float4* o = reinterpret_cast<float4*>(out + (size_t)i1 * E);
        o[0] = make_float4(mu[1][0],  mu[1][1],  mu[1][2],  mu[1][3]);
        o[1] = make_float4(mu[1][4],  mu[1][5],  mu[1][6],  mu[1][7]);
        o[2] = make_float4(mu[1][8],  mu[1][9],  mu[1][10], mu[1][11]);
        o[3] = make_float4(mu[1][12], mu[1][13], mu[1][14], mu[1][15]);
    }
}

extern "C" void kernel_launch(void* const* d_in, const int* in_sizes, int n_in,
                              void* d_out, int out_size, void* d_ws, size_t ws_size,
                              hipStream_t stream) {
    const float* x   = (const float*)d_in[0];
    const float* G   = (const float*)d_in[1];
    const float* h   = (const float*)d_in[2];
    const float* W1  = (const float*)d_in[3];
    const float* b1  = (const float*)d_in[4];
    const float* W2  = (const float*)d_in[5];
    const float* b2  = (const float*)d_in[6];
    const float* Wmu = (const float*)d_in[7];
    const float* bmu = (const float*)d_in[8];
    const float* Wy  = (const float*)d_in[9];
    const float* by  = (const float*)d_in[10];
    const float* Wp1 = (const float*)d_in[11];
    const float* bp1 = (const float*)d_in[12];
    const float* Wp2 = (const float*)d_in[13];
    const float* bp2 = (const float*)d_in[14];

    const int npts = in_sizes[0] / 2;   // x is [N,2]
    const int half = (npts + 1) >> 1;   // P=2 points per thread
    const int block = 256;
    const int grid = (half + block - 1) / block;

    pdhg_kernel<<<grid, block, 0, stream>>>(x, G, h, W1, b1, W2, b2, Wmu, bmu,
                                            Wy, by, Wp1, bp1, Wp2, bp2,
                                            (float*)d_out, npts);
}